// Round 20
// baseline (78.877 us; speedup 1.0000x reference)
//
#include <hip/hip_runtime.h>
#include <stdint.h>

// Problem constants
#define NN 16384                  // sampled points per batch (h*w)
#define HW 65536                  // H*W
#define OUT_HALF (2 * NN * 128)   // one tuple element, flat floats
#define NP 2                      // points per wave (plain sequential loop)
// MLP: 67 -> 64 -> 64 -> 128 (BN folded), maxpool over K=32 neighbors.
//
// Round-20 = EXACT round-19 body (74.6 us, absmax 1.22e-4, no spill) with
// ONE structural change: each wave processes NP=2 points via a plain
// #pragma unroll 1 loop (no cross-iteration state -- not r6/r7/r12's
// staging-register trap). Grid 4096->2048: block generations per CU 16->8,
// LDS fill bytes per point 4KB->2KB, while 2048 blocks still give 8
// replacement waves of 4 blocks/CU (r15 lesson: exact-fit grids tail-stall).
// Everything else identical to r19: sequential-mt single-acc all layers
// (fits the 64-combined-reg budget, no scratch), 32 KiB hi-only LDS image,
// launch_bounds(512,8), 1-pass full-bf16 MFMA, bias/X0 global, XCD swizzle.
//
// Dataflow (m74/m101-verified maps):
//   L0/L1 operand-swapped (A=W, B=act) -> C/D col = lane&31 = neighbor.
//   Transitions in-register: relu -> cvt_pk -> permlane32_swap.
//   L2 normal (A=act, B=W); maxpool = 16 fmax + xor(32); kh halves store the
//   two tuple copies.
//
// Fragment maps (gfx950 32x32x16 bf16):
//   A: row = lane&31, k = 8*(lane>>5)+e ;  B: col = lane&31, same k
//   C/D: col = lane&31, row = (rg&3) + 8*(rg>>2) + 4*(lane>>5)

typedef __attribute__((ext_vector_type(8)))  short bf16x8;
typedef __attribute__((ext_vector_type(16))) float f32x16;

// ws layout, uint16 units (IDENTICAL to rounds 11/14/16-19):
#define WS_L0H 0
#define WS_L0L 4096
#define WS_L1H 8192
#define WS_L1L 12288
#define WS_L2H 16384
#define WS_L2L 24576
#define WS_X0H 32768
#define WS_X0L 33792
#define WS_BIAS 34816

// LDS compacted image (hi-only), uint16 units:
#define LDS_L0H 0                 // 4096
#define LDS_L1H 4096              // 4096
#define LDS_L2H 8192              // 8192
#define LDS_U16 16384             // 32 KiB

__device__ inline uint16_t f32_to_bf16_rne(float x) {
    uint32_t u = __float_as_uint(x);
    uint32_t r = (u + 0x7FFFu + ((u >> 16) & 1u)) >> 16;
    return (uint16_t)r;
}
__device__ inline float bf16_hi_f32(uint16_t h) {
    return __uint_as_float(((uint32_t)h) << 16);
}
__device__ inline void split2(float v, uint16_t* hi, uint16_t* lo) {
    uint16_t h = f32_to_bf16_rne(v);
    *hi = h;
    *lo = f32_to_bf16_rne(v - bf16_hi_f32(h));
}

// ---------------- weight prep (runs once per launch, tiny) ----------------
// BYTE-IDENTICAL to rounds 11/14/16-19.
__global__ void prep_weights(
    const float* __restrict__ W0, const float* __restrict__ b0,
    const float* __restrict__ g0, const float* __restrict__ be0,
    const float* __restrict__ W1, const float* __restrict__ b1,
    const float* __restrict__ g1, const float* __restrict__ be1,
    const float* __restrict__ W2, const float* __restrict__ b2,
    const float* __restrict__ g2, const float* __restrict__ be2,
    uint16_t* __restrict__ ws)
{
    const int tid = blockIdx.x * blockDim.x + threadIdx.x;
    const int nth = gridDim.x * blockDim.x;

    for (int i = tid; i < 4096; i += nth) {
        int e = i & 7, lane = (i >> 3) & 63, nt = (i >> 9) & 1, kt = i >> 10;
        int k = kt * 16 + 8 * (lane >> 5) + e;
        int n = nt * 32 + (lane & 31);
        float v = W0[(3 + k) * 64 + n] * g0[n];
        uint16_t hi, lo; split2(v, &hi, &lo);
        ws[WS_L0H + i] = hi; ws[WS_L0L + i] = lo;
    }
    for (int i = tid; i < 1024; i += nth) {
        int e = i & 7, lane = (i >> 3) & 63, nt = i >> 9;
        int k = 64 + 8 * (lane >> 5) + e;
        int n = nt * 32 + (lane & 31);
        float v = (k < 67) ? W0[(k - 64) * 64 + n] * g0[n] : 0.f;
        uint16_t hi, lo; split2(v, &hi, &lo);
        ws[WS_X0H + i] = hi; ws[WS_X0L + i] = lo;
    }
    for (int i = tid; i < 4096; i += nth) {
        int e = i & 7, lane = (i >> 3) & 63, nt = (i >> 9) & 1, kt = i >> 10;
        int k = kt * 16 + 8 * (lane >> 5) + e;
        int n = nt * 32 + (lane & 31);
        float v = W1[k * 64 + n] * g1[n];
        uint16_t hi, lo; split2(v, &hi, &lo);
        ws[WS_L1H + i] = hi; ws[WS_L1L + i] = lo;
    }
    for (int i = tid; i < 8192; i += nth) {
        int e = i & 7, lane = (i >> 3) & 63, nt = (i >> 9) & 3, kt = i >> 11;
        int k = kt * 16 + 8 * (lane >> 5) + e;
        int n = nt * 32 + (lane & 31);
        float v = W2[k * 128 + n] * g2[n];
        uint16_t hi, lo; split2(v, &hi, &lo);
        ws[WS_L2H + i] = hi; ws[WS_L2L + i] = lo;
    }
    float* bias = (float*)(ws + WS_BIAS);
    for (int i = tid; i < 64; i += nth)  bias[i]       = b0[i] * g0[i] + be0[i];
    for (int i = tid; i < 64; i += nth)  bias[64 + i]  = b1[i] * g1[i] + be1[i];
    for (int i = tid; i < 128; i += nth) bias[128 + i] = b2[i] * g2[i] + be2[i];
}

// ---------------- main kernel helpers ----------------
__device__ inline uint32_t cvt_pk_bf16(float a, float b) {
    uint32_t r;
    asm("v_cvt_pk_bf16_f32 %0, %1, %2" : "=v"(r) : "v"(a), "v"(b));
    return r;
}

union frag_u { uint32_t w[4]; bf16x8 v; };

// convert 8 f32 -> bf16x8 (RNE) via packed converts
__device__ inline bf16x8 cvt8(const float* f) {
    frag_u H;
    #pragma unroll
    for (int p2 = 0; p2 < 4; ++p2)
        H.w[p2] = cvt_pk_bf16(f[2 * p2], f[2 * p2 + 1]);
    return H.v;
}

// relu + bf16 convert + permlane32_swap for ONE mt accumulator ->
// two kt-indexed K-fragments.
__device__ inline void trans1(const f32x16& acc, bf16x8* f0, bf16x8* f1) {
    uint32_t H[8];
    #pragma unroll
    for (int w = 0; w < 8; ++w) {
        float a = fmaxf(acc[2 * w],     0.f);
        float b = fmaxf(acc[2 * w + 1], 0.f);
        H[w] = cvt_pk_bf16(a, b);
    }
    {
        uint32_t a0 = H[0], b0 = H[2], a1 = H[1], b1 = H[3];
        asm("v_permlane32_swap_b32 %0, %1" : "+v"(a0), "+v"(b0));
        asm("v_permlane32_swap_b32 %0, %1" : "+v"(a1), "+v"(b1));
        frag_u F; F.w[0] = a0; F.w[1] = a1; F.w[2] = b0; F.w[3] = b1;
        *f0 = F.v;
    }
    {
        uint32_t a0 = H[4], b0 = H[6], a1 = H[5], b1 = H[7];
        asm("v_permlane32_swap_b32 %0, %1" : "+v"(a0), "+v"(b0));
        asm("v_permlane32_swap_b32 %0, %1" : "+v"(a1), "+v"(b1));
        frag_u F; F.w[0] = a0; F.w[1] = a1; F.w[2] = b0; F.w[3] = b1;
        *f1 = F.v;
    }
}

__global__ __launch_bounds__(512, 8)
void pointnet_mfma(
    const float* __restrict__ xyz_proj,      // [B, H*W, 3]
    const float* __restrict__ points_proj,   // [B, H*W, 64]
    const float* __restrict__ xyz_sampled,   // [B, N, 3]
    const int*   __restrict__ nidx,          // [B, N, 32]
    const float* __restrict__ vmask,         // [B, N, 32, 1]
    const uint16_t* __restrict__ wf,
    float* __restrict__ out)
{
    __shared__ __align__(16) uint16_t slds[LDS_U16];   // 32 KiB hi-only image

    // ---- cooperative fill: 3 disjoint hi chunks -> contiguous LDS ----
    {
        const uint4* src = (const uint4*)wf;
        uint4* dst = (uint4*)slds;
        #pragma unroll
        for (int j = 0; j < 4; ++j) {
            int i = threadIdx.x + j * 512;
            int s = (i < 512) ? i : (i < 1024 ? i + 512 : i + 1024);
            dst[i] = src[s];
        }
    }
    __syncthreads();   // only barrier; waves independent afterwards

    // XCD-aware bijective swizzle (grid 2048, 8 XCDs, 256 blocks per XCD)
    const int bid = blockIdx.x;
    const int swz = (bid & 7) * 256 + (bid >> 3);

    const int t     = threadIdx.x & 63;
    const int widx  = threadIdx.x >> 6;        // 0..7
    const int pbase = (swz * 8 + widx) * NP;   // NP consecutive points

    const int r  = t & 31;   // this lane's neighbor (col) all the way through
    const int kh = t >> 5;   // k-half selector

    const bf16x8* L0h = (const bf16x8*)(slds + LDS_L0H);
    const bf16x8* L1h = (const bf16x8*)(slds + LDS_L1H);
    const bf16x8* L2h = (const bf16x8*)(slds + LDS_L2H);
    const bf16x8* X0h = (const bf16x8*)(wf + WS_X0H);   // xyz step: global
    const float*  bias = (const float*)(wf + WS_BIAS);  // bias: global

    #pragma unroll 1
    for (int it = 0; it < NP; ++it) {
        const int p  = pbase + it;
        const int rb = (p >> 14) << 16;        // b * HW

        // ---- per-neighbor scalars (each lane: its own neighbor) ----
        const int   idx = nidx[(size_t)p * 32 + r];
        const float m   = vmask[(size_t)p * 32 + r];
        float xd0, xd1, xd2;
        {
            const float* xs = xyz_proj + (size_t)(rb + idx) * 3;
            const float* ns = xyz_sampled + (size_t)p * 3;
            xd0 = xs[0] * m - ns[0];
            xd1 = xs[1] * m - ns[1];
            xd2 = xs[2] * m - ns[2];
        }
        const float* rowp = points_proj + (size_t)(rb + idx) * 64 + 8 * kh;

        // ---- gather activations ONCE into bh[4] (reused by both mt) ----
        bf16x8 bh[4];
        #pragma unroll
        for (int kt = 0; kt < 4; ++kt) {
            float f[8];
            *(float4*)&f[0] = ((const float4*)(rowp + kt * 16))[0];
            *(float4*)&f[4] = ((const float4*)(rowp + kt * 16))[1];
            #pragma unroll
            for (int e = 0; e < 8; ++e) f[e] *= m;
            bh[kt] = cvt8(f);
        }

        // ---- layer 0 (sequential mt, single acc) -> fh[4] ----
        bf16x8 fh[4];
        #pragma unroll
        for (int mt = 0; mt < 2; ++mt) {
            f32x16 acc;
            #pragma unroll
            for (int q = 0; q < 4; ++q) {
                float4 bq = *(const float4*)(bias + mt * 32 + 4 * kh + 8 * q);
                acc[4 * q + 0] = bq.x; acc[4 * q + 1] = bq.y;
                acc[4 * q + 2] = bq.z; acc[4 * q + 3] = bq.w;
            }
            #pragma unroll
            for (int kt = 0; kt < 4; ++kt) {
                bf16x8 w = L0h[(kt * 2 + mt) * 64 + t];
                acc = __builtin_amdgcn_mfma_f32_32x32x16_bf16(w, bh[kt], acc, 0, 0, 0);
            }
            {   // xyz k-step (k 64..66 live in kh==0 lanes, e<3)
                bf16x8 w = X0h[mt * 64 + t];
                const bool lo32 = (kh == 0);
                float f[8] = { lo32 ? xd0 : 0.f, lo32 ? xd1 : 0.f,
                               lo32 ? xd2 : 0.f, 0.f, 0.f, 0.f, 0.f, 0.f };
                bf16x8 bx = cvt8(f);
                acc = __builtin_amdgcn_mfma_f32_32x32x16_bf16(w, bx, acc, 0, 0, 0);
            }
            trans1(acc, &fh[mt * 2 + 0], &fh[mt * 2 + 1]);
        }

        // ---- layer 1 (sequential mt, single acc) -> gh[4] ----
        bf16x8 gh[4];
        #pragma unroll
        for (int mt = 0; mt < 2; ++mt) {
            f32x16 acc;
            #pragma unroll
            for (int q = 0; q < 4; ++q) {
                float4 bq = *(const float4*)(bias + 64 + mt * 32 + 4 * kh + 8 * q);
                acc[4 * q + 0] = bq.x; acc[4 * q + 1] = bq.y;
                acc[4 * q + 2] = bq.z; acc[4 * q + 3] = bq.w;
            }
            #pragma unroll
            for (int kt = 0; kt < 4; ++kt) {
                bf16x8 w = L1h[(kt * 2 + mt) * 64 + t];
                acc = __builtin_amdgcn_mfma_f32_32x32x16_bf16(w, fh[kt], acc, 0, 0, 0);
            }
            trans1(acc, &gh[mt * 2 + 0], &gh[mt * 2 + 1]);
        }

        // ---- layer 2: 64 -> 128, normal (act=A); fully sequential ----
        #pragma unroll
        for (int half = 0; half < 2; ++half) {
            #pragma unroll
            for (int j = 0; j < 2; ++j) {
                f32x16 acc;
                const float bb = bias[128 + (half * 2 + j) * 32 + r];
                #pragma unroll
                for (int i = 0; i < 16; ++i) acc[i] = bb;
                #pragma unroll
                for (int kt = 0; kt < 4; ++kt) {
                    bf16x8 w = L2h[(kt * 4 + half * 2 + j) * 64 + t];
                    acc = __builtin_amdgcn_mfma_f32_32x32x16_bf16(gh[kt], w, acc, 0, 0, 0);
                }
                float v = acc[0];
                #pragma unroll
                for (int g = 1; g < 16; ++g) v = fmaxf(v, acc[g]);
                v = fmaxf(v, __shfl_xor(v, 32));   // merge kh halves
                v = fmaxf(v, 0.f);                 // relu commutes with max
                // kh=0 lanes store tuple copy 0, kh=1 lanes store copy 1
                size_t o = (size_t)p * 128 + (half * 2 + j) * 32 + r
                         + (size_t)kh * OUT_HALF;
                out[o] = v;
            }
        }
    }
}

extern "C" void kernel_launch(void* const* d_in, const int* in_sizes, int n_in,
                              void* d_out, int out_size, void* d_ws, size_t ws_size,
                              hipStream_t stream) {
    const float* xyz_proj    = (const float*)d_in[0];
    const float* points_proj = (const float*)d_in[1];
    const float* xyz_sampled = (const float*)d_in[2];
    const int*   neighbor_idx= (const int*)  d_in[3];
    const float* valid_mask  = (const float*)d_in[4];
    const float* W0 = (const float*)d_in[5];
    const float* b0 = (const float*)d_in[6];
    const float* g0 = (const float*)d_in[7];
    const float* be0= (const float*)d_in[8];
    const float* W1 = (const float*)d_in[9];
    const float* b1 = (const float*)d_in[10];
    const float* g1 = (const float*)d_in[11];
    const float* be1= (const float*)d_in[12];
    const float* W2 = (const float*)d_in[13];
    const float* b2 = (const float*)d_in[14];
    const float* g2 = (const float*)d_in[15];
    const float* be2= (const float*)d_in[16];

    uint16_t* ws = (uint16_t*)d_ws;

    prep_weights<<<64, 256, 0, stream>>>(W0, b0, g0, be0,
                                         W1, b1, g1, be1,
                                         W2, b2, g2, be2, ws);

    // 32768 points: 2 per wave, 8 waves per block -> 2048 blocks
    pointnet_mfma<<<2048, 512, 0, stream>>>(
        xyz_proj, points_proj, xyz_sampled, neighbor_idx, valid_mask,
        ws, (float*)d_out);
}

// Round 21
// 74.683 us; speedup vs baseline: 1.0561x; 1.0561x over previous
//
#include <hip/hip_runtime.h>
#include <stdint.h>

// Problem constants
#define NN 16384                  // sampled points per batch (h*w)
#define HW 65536                  // H*W
#define OUT_HALF (2 * NN * 128)   // one tuple element, flat floats
// MLP: 67 -> 64 -> 64 -> 128 (BN folded), maxpool over K=32 neighbors.
//
// Round-21 = BYTE-IDENTICAL revert to round 19 (74.6 us, absmax 1.22e-4,
// no spill) -- the best verified kernel. r20's NP=2 loop reintroduced
// partial spill (FETCH 125->147 MB, WRITE 32.8->49 MB): loop-carried
// pbase/pointer state pushed the live-set over the 64-combined-reg budget.
// Structure: one wave = one point; sequential-mt single-f32x16-acc in all
// layers (16 AGPR max live, fits 64-reg budget with zero scratch);
// 32 KiB hi-only weight image in LDS (4 blocks/CU); launch_bounds(512,8)
// (32-wave/CU cap, measured occ 76%); 1-pass full-bf16 MFMA; bias/X0
// global; XCD swizzle; grid 4096 (replacement-friendly).
//
// Dataflow (m74/m101-verified maps):
//   L0/L1 operand-swapped (A=W, B=act) -> C/D col = lane&31 = neighbor.
//   Transitions in-register: relu -> cvt_pk -> permlane32_swap.
//   L2 normal (A=act, B=W); maxpool = 16 fmax + xor(32); kh halves store the
//   two tuple copies.
//
// Fragment maps (gfx950 32x32x16 bf16):
//   A: row = lane&31, k = 8*(lane>>5)+e ;  B: col = lane&31, same k
//   C/D: col = lane&31, row = (rg&3) + 8*(rg>>2) + 4*(lane>>5)

typedef __attribute__((ext_vector_type(8)))  short bf16x8;
typedef __attribute__((ext_vector_type(16))) float f32x16;

// ws layout, uint16 units (IDENTICAL to rounds 11/14/16-19):
#define WS_L0H 0
#define WS_L0L 4096
#define WS_L1H 8192
#define WS_L1L 12288
#define WS_L2H 16384
#define WS_L2L 24576
#define WS_X0H 32768
#define WS_X0L 33792
#define WS_BIAS 34816

// LDS compacted image (hi-only), uint16 units:
#define LDS_L0H 0                 // 4096
#define LDS_L1H 4096              // 4096
#define LDS_L2H 8192              // 8192
#define LDS_U16 16384             // 32 KiB

__device__ inline uint16_t f32_to_bf16_rne(float x) {
    uint32_t u = __float_as_uint(x);
    uint32_t r = (u + 0x7FFFu + ((u >> 16) & 1u)) >> 16;
    return (uint16_t)r;
}
__device__ inline float bf16_hi_f32(uint16_t h) {
    return __uint_as_float(((uint32_t)h) << 16);
}
__device__ inline void split2(float v, uint16_t* hi, uint16_t* lo) {
    uint16_t h = f32_to_bf16_rne(v);
    *hi = h;
    *lo = f32_to_bf16_rne(v - bf16_hi_f32(h));
}

// ---------------- weight prep (runs once per launch, tiny) ----------------
// BYTE-IDENTICAL to rounds 11/14/16-19.
__global__ void prep_weights(
    const float* __restrict__ W0, const float* __restrict__ b0,
    const float* __restrict__ g0, const float* __restrict__ be0,
    const float* __restrict__ W1, const float* __restrict__ b1,
    const float* __restrict__ g1, const float* __restrict__ be1,
    const float* __restrict__ W2, const float* __restrict__ b2,
    const float* __restrict__ g2, const float* __restrict__ be2,
    uint16_t* __restrict__ ws)
{
    const int tid = blockIdx.x * blockDim.x + threadIdx.x;
    const int nth = gridDim.x * blockDim.x;

    for (int i = tid; i < 4096; i += nth) {
        int e = i & 7, lane = (i >> 3) & 63, nt = (i >> 9) & 1, kt = i >> 10;
        int k = kt * 16 + 8 * (lane >> 5) + e;
        int n = nt * 32 + (lane & 31);
        float v = W0[(3 + k) * 64 + n] * g0[n];
        uint16_t hi, lo; split2(v, &hi, &lo);
        ws[WS_L0H + i] = hi; ws[WS_L0L + i] = lo;
    }
    for (int i = tid; i < 1024; i += nth) {
        int e = i & 7, lane = (i >> 3) & 63, nt = i >> 9;
        int k = 64 + 8 * (lane >> 5) + e;
        int n = nt * 32 + (lane & 31);
        float v = (k < 67) ? W0[(k - 64) * 64 + n] * g0[n] : 0.f;
        uint16_t hi, lo; split2(v, &hi, &lo);
        ws[WS_X0H + i] = hi; ws[WS_X0L + i] = lo;
    }
    for (int i = tid; i < 4096; i += nth) {
        int e = i & 7, lane = (i >> 3) & 63, nt = (i >> 9) & 1, kt = i >> 10;
        int k = kt * 16 + 8 * (lane >> 5) + e;
        int n = nt * 32 + (lane & 31);
        float v = W1[k * 64 + n] * g1[n];
        uint16_t hi, lo; split2(v, &hi, &lo);
        ws[WS_L1H + i] = hi; ws[WS_L1L + i] = lo;
    }
    for (int i = tid; i < 8192; i += nth) {
        int e = i & 7, lane = (i >> 3) & 63, nt = (i >> 9) & 3, kt = i >> 11;
        int k = kt * 16 + 8 * (lane >> 5) + e;
        int n = nt * 32 + (lane & 31);
        float v = W2[k * 128 + n] * g2[n];
        uint16_t hi, lo; split2(v, &hi, &lo);
        ws[WS_L2H + i] = hi; ws[WS_L2L + i] = lo;
    }
    float* bias = (float*)(ws + WS_BIAS);
    for (int i = tid; i < 64; i += nth)  bias[i]       = b0[i] * g0[i] + be0[i];
    for (int i = tid; i < 64; i += nth)  bias[64 + i]  = b1[i] * g1[i] + be1[i];
    for (int i = tid; i < 128; i += nth) bias[128 + i] = b2[i] * g2[i] + be2[i];
}

// ---------------- main kernel helpers ----------------
__device__ inline uint32_t cvt_pk_bf16(float a, float b) {
    uint32_t r;
    asm("v_cvt_pk_bf16_f32 %0, %1, %2" : "=v"(r) : "v"(a), "v"(b));
    return r;
}

union frag_u { uint32_t w[4]; bf16x8 v; };

// convert 8 f32 -> bf16x8 (RNE) via packed converts
__device__ inline bf16x8 cvt8(const float* f) {
    frag_u H;
    #pragma unroll
    for (int p2 = 0; p2 < 4; ++p2)
        H.w[p2] = cvt_pk_bf16(f[2 * p2], f[2 * p2 + 1]);
    return H.v;
}

// relu + bf16 convert + permlane32_swap for ONE mt accumulator ->
// two kt-indexed K-fragments.
__device__ inline void trans1(const f32x16& acc, bf16x8* f0, bf16x8* f1) {
    uint32_t H[8];
    #pragma unroll
    for (int w = 0; w < 8; ++w) {
        float a = fmaxf(acc[2 * w],     0.f);
        float b = fmaxf(acc[2 * w + 1], 0.f);
        H[w] = cvt_pk_bf16(a, b);
    }
    {
        uint32_t a0 = H[0], b0 = H[2], a1 = H[1], b1 = H[3];
        asm("v_permlane32_swap_b32 %0, %1" : "+v"(a0), "+v"(b0));
        asm("v_permlane32_swap_b32 %0, %1" : "+v"(a1), "+v"(b1));
        frag_u F; F.w[0] = a0; F.w[1] = a1; F.w[2] = b0; F.w[3] = b1;
        *f0 = F.v;
    }
    {
        uint32_t a0 = H[4], b0 = H[6], a1 = H[5], b1 = H[7];
        asm("v_permlane32_swap_b32 %0, %1" : "+v"(a0), "+v"(b0));
        asm("v_permlane32_swap_b32 %0, %1" : "+v"(a1), "+v"(b1));
        frag_u F; F.w[0] = a0; F.w[1] = a1; F.w[2] = b0; F.w[3] = b1;
        *f1 = F.v;
    }
}

__global__ __launch_bounds__(512, 8)
void pointnet_mfma(
    const float* __restrict__ xyz_proj,      // [B, H*W, 3]
    const float* __restrict__ points_proj,   // [B, H*W, 64]
    const float* __restrict__ xyz_sampled,   // [B, N, 3]
    const int*   __restrict__ nidx,          // [B, N, 32]
    const float* __restrict__ vmask,         // [B, N, 32, 1]
    const uint16_t* __restrict__ wf,
    float* __restrict__ out)
{
    __shared__ __align__(16) uint16_t slds[LDS_U16];   // 32 KiB hi-only image

    // ---- cooperative fill: 3 disjoint hi chunks -> contiguous LDS ----
    {
        const uint4* src = (const uint4*)wf;
        uint4* dst = (uint4*)slds;
        #pragma unroll
        for (int j = 0; j < 4; ++j) {
            int i = threadIdx.x + j * 512;
            int s = (i < 512) ? i : (i < 1024 ? i + 512 : i + 1024);
            dst[i] = src[s];
        }
    }
    __syncthreads();   // only barrier; waves independent afterwards

    // XCD-aware bijective swizzle (grid 4096, 8 XCDs, 512 blocks per XCD)
    const int bid = blockIdx.x;
    const int swz = (bid & 7) * 512 + (bid >> 3);

    const int t    = threadIdx.x & 63;
    const int widx = threadIdx.x >> 6;       // 0..7
    const int p    = swz * 8 + widx;          // point id in [0, 2*NN)
    const int rb   = (p >> 14) << 16;          // b * HW

    const int r  = t & 31;   // this lane's neighbor (col) all the way through
    const int kh = t >> 5;   // k-half selector

    const bf16x8* L0h = (const bf16x8*)(slds + LDS_L0H);
    const bf16x8* L1h = (const bf16x8*)(slds + LDS_L1H);
    const bf16x8* L2h = (const bf16x8*)(slds + LDS_L2H);
    const bf16x8* X0h = (const bf16x8*)(wf + WS_X0H);   // xyz step: global
    const float*  bias = (const float*)(wf + WS_BIAS);  // bias: global

    // ---- per-neighbor scalars (each lane: its own neighbor) ----
    const int   idx = nidx[(size_t)p * 32 + r];
    const float m   = vmask[(size_t)p * 32 + r];
    float xd0, xd1, xd2;
    {
        const float* xs = xyz_proj + (size_t)(rb + idx) * 3;
        const float* ns = xyz_sampled + (size_t)p * 3;
        xd0 = xs[0] * m - ns[0];
        xd1 = xs[1] * m - ns[1];
        xd2 = xs[2] * m - ns[2];
    }
    const float* rowp = points_proj + (size_t)(rb + idx) * 64 + 8 * kh;

    // ---- gather activations ONCE into bh[4] (reused by both mt passes) ----
    bf16x8 bh[4];
    #pragma unroll
    for (int kt = 0; kt < 4; ++kt) {
        float f[8];
        *(float4*)&f[0] = ((const float4*)(rowp + kt * 16))[0];
        *(float4*)&f[4] = ((const float4*)(rowp + kt * 16))[1];
        #pragma unroll
        for (int e = 0; e < 8; ++e) f[e] *= m;
        bh[kt] = cvt8(f);
    }

    // ---- layer 0 (sequential mt, single acc) -> fh[4] ----
    bf16x8 fh[4];
    #pragma unroll
    for (int mt = 0; mt < 2; ++mt) {
        f32x16 acc;
        #pragma unroll
        for (int q = 0; q < 4; ++q) {
            float4 bq = *(const float4*)(bias + mt * 32 + 4 * kh + 8 * q);
            acc[4 * q + 0] = bq.x; acc[4 * q + 1] = bq.y;
            acc[4 * q + 2] = bq.z; acc[4 * q + 3] = bq.w;
        }
        #pragma unroll
        for (int kt = 0; kt < 4; ++kt) {
            bf16x8 w = L0h[(kt * 2 + mt) * 64 + t];
            acc = __builtin_amdgcn_mfma_f32_32x32x16_bf16(w, bh[kt], acc, 0, 0, 0);
        }
        {   // xyz k-step (k 64..66 live in kh==0 lanes, e<3); transient frag
            bf16x8 w = X0h[mt * 64 + t];
            const bool lo32 = (kh == 0);
            float f[8] = { lo32 ? xd0 : 0.f, lo32 ? xd1 : 0.f, lo32 ? xd2 : 0.f,
                           0.f, 0.f, 0.f, 0.f, 0.f };
            bf16x8 bx = cvt8(f);
            acc = __builtin_amdgcn_mfma_f32_32x32x16_bf16(w, bx, acc, 0, 0, 0);
        }
        trans1(acc, &fh[mt * 2 + 0], &fh[mt * 2 + 1]);
    }

    // ---- layer 1 (sequential mt, single acc) -> gh[4] ----
    bf16x8 gh[4];
    #pragma unroll
    for (int mt = 0; mt < 2; ++mt) {
        f32x16 acc;
        #pragma unroll
        for (int q = 0; q < 4; ++q) {
            float4 bq = *(const float4*)(bias + 64 + mt * 32 + 4 * kh + 8 * q);
            acc[4 * q + 0] = bq.x; acc[4 * q + 1] = bq.y;
            acc[4 * q + 2] = bq.z; acc[4 * q + 3] = bq.w;
        }
        #pragma unroll
        for (int kt = 0; kt < 4; ++kt) {
            bf16x8 w = L1h[(kt * 2 + mt) * 64 + t];
            acc = __builtin_amdgcn_mfma_f32_32x32x16_bf16(w, fh[kt], acc, 0, 0, 0);
        }
        trans1(acc, &gh[mt * 2 + 0], &gh[mt * 2 + 1]);
    }

    // ---- layer 2: 64 -> 128, normal (act=A); fully sequential ----
    #pragma unroll
    for (int half = 0; half < 2; ++half) {
        #pragma unroll
        for (int j = 0; j < 2; ++j) {
            f32x16 acc;
            const float bb = bias[128 + (half * 2 + j) * 32 + r];
            #pragma unroll
            for (int i = 0; i < 16; ++i) acc[i] = bb;
            #pragma unroll
            for (int kt = 0; kt < 4; ++kt) {
                bf16x8 w = L2h[(kt * 4 + half * 2 + j) * 64 + t];
                acc = __builtin_amdgcn_mfma_f32_32x32x16_bf16(gh[kt], w, acc, 0, 0, 0);
            }
            float v = acc[0];
            #pragma unroll
            for (int g = 1; g < 16; ++g) v = fmaxf(v, acc[g]);
            v = fmaxf(v, __shfl_xor(v, 32));   // merge kh halves
            v = fmaxf(v, 0.f);                 // relu commutes with max
            // kh=0 lanes store tuple copy 0, kh=1 lanes store copy 1
            size_t o = (size_t)p * 128 + (half * 2 + j) * 32 + r
                     + (size_t)kh * OUT_HALF;
            out[o] = v;
        }
    }
}

extern "C" void kernel_launch(void* const* d_in, const int* in_sizes, int n_in,
                              void* d_out, int out_size, void* d_ws, size_t ws_size,
                              hipStream_t stream) {
    const float* xyz_proj    = (const float*)d_in[0];
    const float* points_proj = (const float*)d_in[1];
    const float* xyz_sampled = (const float*)d_in[2];
    const int*   neighbor_idx= (const int*)  d_in[3];
    const float* valid_mask  = (const float*)d_in[4];
    const float* W0 = (const float*)d_in[5];
    const float* b0 = (const float*)d_in[6];
    const float* g0 = (const float*)d_in[7];
    const float* be0= (const float*)d_in[8];
    const float* W1 = (const float*)d_in[9];
    const float* b1 = (const float*)d_in[10];
    const float* g1 = (const float*)d_in[11];
    const float* be1= (const float*)d_in[12];
    const float* W2 = (const float*)d_in[13];
    const float* b2 = (const float*)d_in[14];
    const float* g2 = (const float*)d_in[15];
    const float* be2= (const float*)d_in[16];

    uint16_t* ws = (uint16_t*)d_ws;

    prep_weights<<<64, 256, 0, stream>>>(W0, b0, g0, be0,
                                         W1, b1, g1, be1,
                                         W2, b2, g2, be2, ws);

    // 32768 points: 1 per wave, 8 waves per block -> 4096 blocks
    pointnet_mfma<<<4096, 512, 0, stream>>>(
        xyz_proj, points_proj, xyz_sampled, neighbor_idx, valid_mask,
        ws, (float*)d_out);
}

// Round 22
// 74.266 us; speedup vs baseline: 1.0621x; 1.0056x over previous
//
#include <hip/hip_runtime.h>
#include <stdint.h>

// Problem constants
#define NN 16384                  // sampled points per batch (h*w)
#define HW 65536                  // H*W
#define OUT_HALF (2 * NN * 128)   // one tuple element, flat floats
// MLP: 67 -> 64 -> 64 -> 128 (BN folded), maxpool over K=32 neighbors.
//
// Round-22 = round-19/21 (74.7 us, absmax 1.22e-4, no spill) with ONE
// change: the per-wave gather chain (idx -> mask -> xyz -> 4x float4
// activation rows) is ISSUED BEFORE the cooperative LDS fill. The
// __syncthreads drain completes those loads under the fill's own memory
// traffic, so compute starts with gather data already in registers --
// removing the ~1400-cyc exposed idx->gather dependency that dominated
// the post-barrier critical path (per-wave issue slot 1400 cyc vs ~800
// cyc pipe work). Mask-mul + cvt8 move post-barrier (bit-identical math).
// Register budget: 32 raw gather + 6 scalars + ~16 fill temps = ~58 < 64.
// Everything else identical to r19: sequential-mt single-acc all layers,
// 32 KiB hi-only LDS image (4 blocks/CU), launch_bounds(512,8), 1-pass
// full-bf16 MFMA, bias/X0 global, XCD swizzle, grid 4096.
//
// Dataflow (m74/m101-verified maps):
//   L0/L1 operand-swapped (A=W, B=act) -> C/D col = lane&31 = neighbor.
//   Transitions in-register: relu -> cvt_pk -> permlane32_swap.
//   L2 normal (A=act, B=W); maxpool = 16 fmax + xor(32); kh halves store the
//   two tuple copies.
//
// Fragment maps (gfx950 32x32x16 bf16):
//   A: row = lane&31, k = 8*(lane>>5)+e ;  B: col = lane&31, same k
//   C/D: col = lane&31, row = (rg&3) + 8*(rg>>2) + 4*(lane>>5)

typedef __attribute__((ext_vector_type(8)))  short bf16x8;
typedef __attribute__((ext_vector_type(16))) float f32x16;

// ws layout, uint16 units (IDENTICAL to rounds 11/14/16-21):
#define WS_L0H 0
#define WS_L0L 4096
#define WS_L1H 8192
#define WS_L1L 12288
#define WS_L2H 16384
#define WS_L2L 24576
#define WS_X0H 32768
#define WS_X0L 33792
#define WS_BIAS 34816

// LDS compacted image (hi-only), uint16 units:
#define LDS_L0H 0                 // 4096
#define LDS_L1H 4096              // 4096
#define LDS_L2H 8192              // 8192
#define LDS_U16 16384             // 32 KiB

__device__ inline uint16_t f32_to_bf16_rne(float x) {
    uint32_t u = __float_as_uint(x);
    uint32_t r = (u + 0x7FFFu + ((u >> 16) & 1u)) >> 16;
    return (uint16_t)r;
}
__device__ inline float bf16_hi_f32(uint16_t h) {
    return __uint_as_float(((uint32_t)h) << 16);
}
__device__ inline void split2(float v, uint16_t* hi, uint16_t* lo) {
    uint16_t h = f32_to_bf16_rne(v);
    *hi = h;
    *lo = f32_to_bf16_rne(v - bf16_hi_f32(h));
}

// ---------------- weight prep (runs once per launch, tiny) ----------------
// BYTE-IDENTICAL to rounds 11/14/16-21.
__global__ void prep_weights(
    const float* __restrict__ W0, const float* __restrict__ b0,
    const float* __restrict__ g0, const float* __restrict__ be0,
    const float* __restrict__ W1, const float* __restrict__ b1,
    const float* __restrict__ g1, const float* __restrict__ be1,
    const float* __restrict__ W2, const float* __restrict__ b2,
    const float* __restrict__ g2, const float* __restrict__ be2,
    uint16_t* __restrict__ ws)
{
    const int tid = blockIdx.x * blockDim.x + threadIdx.x;
    const int nth = gridDim.x * blockDim.x;

    for (int i = tid; i < 4096; i += nth) {
        int e = i & 7, lane = (i >> 3) & 63, nt = (i >> 9) & 1, kt = i >> 10;
        int k = kt * 16 + 8 * (lane >> 5) + e;
        int n = nt * 32 + (lane & 31);
        float v = W0[(3 + k) * 64 + n] * g0[n];
        uint16_t hi, lo; split2(v, &hi, &lo);
        ws[WS_L0H + i] = hi; ws[WS_L0L + i] = lo;
    }
    for (int i = tid; i < 1024; i += nth) {
        int e = i & 7, lane = (i >> 3) & 63, nt = i >> 9;
        int k = 64 + 8 * (lane >> 5) + e;
        int n = nt * 32 + (lane & 31);
        float v = (k < 67) ? W0[(k - 64) * 64 + n] * g0[n] : 0.f;
        uint16_t hi, lo; split2(v, &hi, &lo);
        ws[WS_X0H + i] = hi; ws[WS_X0L + i] = lo;
    }
    for (int i = tid; i < 4096; i += nth) {
        int e = i & 7, lane = (i >> 3) & 63, nt = (i >> 9) & 1, kt = i >> 10;
        int k = kt * 16 + 8 * (lane >> 5) + e;
        int n = nt * 32 + (lane & 31);
        float v = W1[k * 64 + n] * g1[n];
        uint16_t hi, lo; split2(v, &hi, &lo);
        ws[WS_L1H + i] = hi; ws[WS_L1L + i] = lo;
    }
    for (int i = tid; i < 8192; i += nth) {
        int e = i & 7, lane = (i >> 3) & 63, nt = (i >> 9) & 3, kt = i >> 11;
        int k = kt * 16 + 8 * (lane >> 5) + e;
        int n = nt * 32 + (lane & 31);
        float v = W2[k * 128 + n] * g2[n];
        uint16_t hi, lo; split2(v, &hi, &lo);
        ws[WS_L2H + i] = hi; ws[WS_L2L + i] = lo;
    }
    float* bias = (float*)(ws + WS_BIAS);
    for (int i = tid; i < 64; i += nth)  bias[i]       = b0[i] * g0[i] + be0[i];
    for (int i = tid; i < 64; i += nth)  bias[64 + i]  = b1[i] * g1[i] + be1[i];
    for (int i = tid; i < 128; i += nth) bias[128 + i] = b2[i] * g2[i] + be2[i];
}

// ---------------- main kernel helpers ----------------
__device__ inline uint32_t cvt_pk_bf16(float a, float b) {
    uint32_t r;
    asm("v_cvt_pk_bf16_f32 %0, %1, %2" : "=v"(r) : "v"(a), "v"(b));
    return r;
}

union frag_u { uint32_t w[4]; bf16x8 v; };

// convert 8 f32 -> bf16x8 (RNE) via packed converts
__device__ inline bf16x8 cvt8(const float* f) {
    frag_u H;
    #pragma unroll
    for (int p2 = 0; p2 < 4; ++p2)
        H.w[p2] = cvt_pk_bf16(f[2 * p2], f[2 * p2 + 1]);
    return H.v;
}

// relu + bf16 convert + permlane32_swap for ONE mt accumulator ->
// two kt-indexed K-fragments.
__device__ inline void trans1(const f32x16& acc, bf16x8* f0, bf16x8* f1) {
    uint32_t H[8];
    #pragma unroll
    for (int w = 0; w < 8; ++w) {
        float a = fmaxf(acc[2 * w],     0.f);
        float b = fmaxf(acc[2 * w + 1], 0.f);
        H[w] = cvt_pk_bf16(a, b);
    }
    {
        uint32_t a0 = H[0], b0 = H[2], a1 = H[1], b1 = H[3];
        asm("v_permlane32_swap_b32 %0, %1" : "+v"(a0), "+v"(b0));
        asm("v_permlane32_swap_b32 %0, %1" : "+v"(a1), "+v"(b1));
        frag_u F; F.w[0] = a0; F.w[1] = a1; F.w[2] = b0; F.w[3] = b1;
        *f0 = F.v;
    }
    {
        uint32_t a0 = H[4], b0 = H[6], a1 = H[5], b1 = H[7];
        asm("v_permlane32_swap_b32 %0, %1" : "+v"(a0), "+v"(b0));
        asm("v_permlane32_swap_b32 %0, %1" : "+v"(a1), "+v"(b1));
        frag_u F; F.w[0] = a0; F.w[1] = a1; F.w[2] = b0; F.w[3] = b1;
        *f1 = F.v;
    }
}

__global__ __launch_bounds__(512, 8)
void pointnet_mfma(
    const float* __restrict__ xyz_proj,      // [B, H*W, 3]
    const float* __restrict__ points_proj,   // [B, H*W, 64]
    const float* __restrict__ xyz_sampled,   // [B, N, 3]
    const int*   __restrict__ nidx,          // [B, N, 32]
    const float* __restrict__ vmask,         // [B, N, 32, 1]
    const uint16_t* __restrict__ wf,
    float* __restrict__ out)
{
    __shared__ __align__(16) uint16_t slds[LDS_U16];   // 32 KiB hi-only image

    // XCD-aware bijective swizzle (grid 4096, 8 XCDs, 512 blocks per XCD)
    const int bid = blockIdx.x;
    const int swz = (bid & 7) * 512 + (bid >> 3);

    const int t    = threadIdx.x & 63;
    const int widx = threadIdx.x >> 6;       // 0..7
    const int p    = swz * 8 + widx;          // point id in [0, 2*NN)
    const int rb   = (p >> 14) << 16;          // b * HW

    const int r  = t & 31;   // this lane's neighbor (col) all the way through
    const int kh = t >> 5;   // k-half selector

    // ---- ISSUE the gather chain BEFORE the fill (r22 change) ----
    const int   idx = nidx[(size_t)p * 32 + r];
    const float m   = vmask[(size_t)p * 32 + r];
    float xs0, xs1, xs2, ns0, ns1, ns2;
    {
        const float* xs = xyz_proj + (size_t)(rb + idx) * 3;
        const float* ns = xyz_sampled + (size_t)p * 3;
        xs0 = xs[0]; xs1 = xs[1]; xs2 = xs[2];
        ns0 = ns[0]; ns1 = ns[1]; ns2 = ns[2];
    }
    const float* rowp = points_proj + (size_t)(rb + idx) * 64 + 8 * kh;
    float4 fr[8];                            // raw gather rows (32 VGPRs)
    #pragma unroll
    for (int kt = 0; kt < 4; ++kt) {
        fr[2 * kt + 0] = ((const float4*)(rowp + kt * 16))[0];
        fr[2 * kt + 1] = ((const float4*)(rowp + kt * 16))[1];
    }

    // ---- cooperative fill: 3 disjoint hi chunks -> contiguous LDS ----
    // (fill traffic streams while the gather loads above are in flight;
    //  __syncthreads drains everything -> compute starts stall-free)
    {
        const uint4* src = (const uint4*)wf;
        uint4* dst = (uint4*)slds;
        #pragma unroll
        for (int j = 0; j < 4; ++j) {
            int i = threadIdx.x + j * 512;
            int s = (i < 512) ? i : (i < 1024 ? i + 512 : i + 1024);
            dst[i] = src[s];
        }
    }
    __syncthreads();   // only barrier; waves independent afterwards

    const bf16x8* L0h = (const bf16x8*)(slds + LDS_L0H);
    const bf16x8* L1h = (const bf16x8*)(slds + LDS_L1H);
    const bf16x8* L2h = (const bf16x8*)(slds + LDS_L2H);
    const bf16x8* X0h = (const bf16x8*)(wf + WS_X0H);   // xyz step: global
    const float*  bias = (const float*)(wf + WS_BIAS);  // bias: global

    // ---- post-barrier: mask-mul + convert (bit-identical to r19) ----
    const float xd0 = xs0 * m - ns0;
    const float xd1 = xs1 * m - ns1;
    const float xd2 = xs2 * m - ns2;

    bf16x8 bh[4];
    #pragma unroll
    for (int kt = 0; kt < 4; ++kt) {
        float f[8];
        f[0] = fr[2*kt].x * m;   f[1] = fr[2*kt].y * m;
        f[2] = fr[2*kt].z * m;   f[3] = fr[2*kt].w * m;
        f[4] = fr[2*kt+1].x * m; f[5] = fr[2*kt+1].y * m;
        f[6] = fr[2*kt+1].z * m; f[7] = fr[2*kt+1].w * m;
        bh[kt] = cvt8(f);
    }

    // ---- layer 0 (sequential mt, single acc) -> fh[4] ----
    bf16x8 fh[4];
    #pragma unroll
    for (int mt = 0; mt < 2; ++mt) {
        f32x16 acc;
        #pragma unroll
        for (int q = 0; q < 4; ++q) {
            float4 bq = *(const float4*)(bias + mt * 32 + 4 * kh + 8 * q);
            acc[4 * q + 0] = bq.x; acc[4 * q + 1] = bq.y;
            acc[4 * q + 2] = bq.z; acc[4 * q + 3] = bq.w;
        }
        #pragma unroll
        for (int kt = 0; kt < 4; ++kt) {
            bf16x8 w = L0h[(kt * 2 + mt) * 64 + t];
            acc = __builtin_amdgcn_mfma_f32_32x32x16_bf16(w, bh[kt], acc, 0, 0, 0);
        }
        {   // xyz k-step (k 64..66 live in kh==0 lanes, e<3); transient frag
            bf16x8 w = X0h[mt * 64 + t];
            const bool lo32 = (kh == 0);
            float f[8] = { lo32 ? xd0 : 0.f, lo32 ? xd1 : 0.f, lo32 ? xd2 : 0.f,
                           0.f, 0.f, 0.f, 0.f, 0.f };
            bf16x8 bx = cvt8(f);
            acc = __builtin_amdgcn_mfma_f32_32x32x16_bf16(w, bx, acc, 0, 0, 0);
        }
        trans1(acc, &fh[mt * 2 + 0], &fh[mt * 2 + 1]);
    }

    // ---- layer 1 (sequential mt, single acc) -> gh[4] ----
    bf16x8 gh[4];
    #pragma unroll
    for (int mt = 0; mt < 2; ++mt) {
        f32x16 acc;
        #pragma unroll
        for (int q = 0; q < 4; ++q) {
            float4 bq = *(const float4*)(bias + 64 + mt * 32 + 4 * kh + 8 * q);
            acc[4 * q + 0] = bq.x; acc[4 * q + 1] = bq.y;
            acc[4 * q + 2] = bq.z; acc[4 * q + 3] = bq.w;
        }
        #pragma unroll
        for (int kt = 0; kt < 4; ++kt) {
            bf16x8 w = L1h[(kt * 2 + mt) * 64 + t];
            acc = __builtin_amdgcn_mfma_f32_32x32x16_bf16(w, fh[kt], acc, 0, 0, 0);
        }
        trans1(acc, &gh[mt * 2 + 0], &gh[mt * 2 + 1]);
    }

    // ---- layer 2: 64 -> 128, normal (act=A); fully sequential ----
    #pragma unroll
    for (int half = 0; half < 2; ++half) {
        #pragma unroll
        for (int j = 0; j < 2; ++j) {
            f32x16 acc;
            const float bb = bias[128 + (half * 2 + j) * 32 + r];
            #pragma unroll
            for (int i = 0; i < 16; ++i) acc[i] = bb;
            #pragma unroll
            for (int kt = 0; kt < 4; ++kt) {
                bf16x8 w = L2h[(kt * 4 + half * 2 + j) * 64 + t];
                acc = __builtin_amdgcn_mfma_f32_32x32x16_bf16(gh[kt], w, acc, 0, 0, 0);
            }
            float v = acc[0];
            #pragma unroll
            for (int g = 1; g < 16; ++g) v = fmaxf(v, acc[g]);
            v = fmaxf(v, __shfl_xor(v, 32));   // merge kh halves
            v = fmaxf(v, 0.f);                 // relu commutes with max
            // kh=0 lanes store tuple copy 0, kh=1 lanes store copy 1
            size_t o = (size_t)p * 128 + (half * 2 + j) * 32 + r
                     + (size_t)kh * OUT_HALF;
            out[o] = v;
        }
    }
}

extern "C" void kernel_launch(void* const* d_in, const int* in_sizes, int n_in,
                              void* d_out, int out_size, void* d_ws, size_t ws_size,
                              hipStream_t stream) {
    const float* xyz_proj    = (const float*)d_in[0];
    const float* points_proj = (const float*)d_in[1];
    const float* xyz_sampled = (const float*)d_in[2];
    const int*   neighbor_idx= (const int*)  d_in[3];
    const float* valid_mask  = (const float*)d_in[4];
    const float* W0 = (const float*)d_in[5];
    const float* b0 = (const float*)d_in[6];
    const float* g0 = (const float*)d_in[7];
    const float* be0= (const float*)d_in[8];
    const float* W1 = (const float*)d_in[9];
    const float* b1 = (const float*)d_in[10];
    const float* g1 = (const float*)d_in[11];
    const float* be1= (const float*)d_in[12];
    const float* W2 = (const float*)d_in[13];
    const float* b2 = (const float*)d_in[14];
    const float* g2 = (const float*)d_in[15];
    const float* be2= (const float*)d_in[16];

    uint16_t* ws = (uint16_t*)d_ws;

    prep_weights<<<64, 256, 0, stream>>>(W0, b0, g0, be0,
                                         W1, b1, g1, be1,
                                         W2, b2, g2, be2, ws);

    // 32768 points: 1 per wave, 8 waves per block -> 4096 blocks
    pointnet_mfma<<<4096, 512, 0, stream>>>(
        xyz_proj, points_proj, xyz_sampled, neighbor_idx, valid_mask,
        ws, (float*)d_out);
}